// Round 2
// baseline (823.615 us; speedup 1.0000x reference)
//
#include <hip/hip_runtime.h>
#include <stdint.h>

typedef unsigned int  u32;
typedef unsigned short u16;

typedef short bf16x8 __attribute__((ext_vector_type(8)));
typedef float f32x4  __attribute__((ext_vector_type(4)));

static __device__ __forceinline__ float b2f(u16 h){
    union { u32 u; float f; } v; v.u = ((u32)h) << 16; return v.f;
}
static __device__ __forceinline__ u16 f2b(float f){
    union { float f; u32 u; } v; v.f = f;
    u32 r = v.u + 0x7FFFu + ((v.u >> 16) & 1u);
    return (u16)(r >> 16);
}

// canonical fp32 weight block offsets (floats)
#define OL0W 0
#define OL0B 384
#define OL1W 768
#define OL1B 49920
#define OL2W 50304
#define OL2B 50688
#define OL3W 51072
#define OL3B 51075
#define OATTW 51078
#define OATTB 83846
#define OSPW 83974
#define OSPB 100358
#define OACW 100486
#define OACB 133254
#define OLASTW 133382
#define OLASTB 133638
#define WTOT 133639

struct Ptrs16 { const void* p[16]; };

// ---- dtype probe: x is exactly {0,1}. fp32 words have low16==0; bf16 pair words
// have low16==0x3F80 about half the time.
__global__ __launch_bounds__(512) void k_detect(const u32* __restrict__ xw, int* __restrict__ flag, int nwords){
    __shared__ int found;
    if (threadIdx.x == 0) found = 0;
    __syncthreads();
    int i = threadIdx.x;
    if (i < nwords && (xw[i] & 0xFFFFu) == 0x3F80u) atomicAdd(&found, 1);
    __syncthreads();
    if (threadIdx.x == 0) *flag = (found > 0) ? 1 : 0;
}

// canonicalize all weights + x to fp32
__global__ __launch_bounds__(256) void k_canon(Ptrs16 wp, const void* __restrict__ xin,
                                               float* __restrict__ wc, float* __restrict__ xc,
                                               const int* __restrict__ flag, int N){
    int i = blockIdx.x * 256 + threadIdx.x;
    int bf = *flag;
    const int sz[16] = {384,384,49152,384,384,384,3,3,32768,128,16384,128,32768,128,256,1};
    if (i < WTOT){
        int seg = 0, off = i;
        while (off >= sz[seg]){ off -= sz[seg]; ++seg; }
        wc[i] = bf ? b2f(((const u16*)wp.p[seg])[off]) : ((const float*)wp.p[seg])[off];
    } else {
        int n = i - WTOT;
        if (n < N) xc[n] = bf ? b2f(((const u16*)xin)[n]) : ((const float*)xin)[n];
    }
}

// ---------------- counting sort of edges by row ----------------

__global__ __launch_bounds__(256) void k_hist(const int* __restrict__ row, int* __restrict__ deg, int E){
    int e = blockIdx.x * 256 + threadIdx.x;
    if (e < E) atomicAdd(&deg[row[e]], 1);
}

__global__ __launch_bounds__(256) void k_scan_a(const int* __restrict__ deg, int* __restrict__ offs,
                                                int* __restrict__ bsum, int N){
    int t = threadIdx.x, b = blockIdx.x;
    int i0 = b * 1024 + t * 4;
    int d0 = (i0 + 0 < N) ? deg[i0 + 0] : 0;
    int d1 = (i0 + 1 < N) ? deg[i0 + 1] : 0;
    int d2 = (i0 + 2 < N) ? deg[i0 + 2] : 0;
    int d3 = (i0 + 3 < N) ? deg[i0 + 3] : 0;
    int s = d0 + d1 + d2 + d3;
    int lane = t & 63, wid = t >> 6;
    int v = s;
    #pragma unroll
    for (int d = 1; d < 64; d <<= 1){ int o = __shfl_up(v, d); if (lane >= d) v += o; }
    __shared__ int wsum[4];
    if (lane == 63) wsum[wid] = v;
    __syncthreads();
    int add = 0;
    for (int w2 = 0; w2 < wid; ++w2) add += wsum[w2];
    v += add;
    int ex = v - s;
    if (i0 + 0 < N) offs[i0 + 0] = ex; ex += d0;
    if (i0 + 1 < N) offs[i0 + 1] = ex; ex += d1;
    if (i0 + 2 < N) offs[i0 + 2] = ex; ex += d2;
    if (i0 + 3 < N) offs[i0 + 3] = ex;
    if (t == 255) bsum[b] = v;
}

__global__ __launch_bounds__(256) void k_scan_b(int* __restrict__ bsum, int nb){
    int t = threadIdx.x;
    int s = (t < nb) ? bsum[t] : 0;
    int lane = t & 63, wid = t >> 6;
    int v = s;
    #pragma unroll
    for (int d = 1; d < 64; d <<= 1){ int o = __shfl_up(v, d); if (lane >= d) v += o; }
    __shared__ int wsum[4];
    if (lane == 63) wsum[wid] = v;
    __syncthreads();
    int add = 0;
    for (int w2 = 0; w2 < wid; ++w2) add += wsum[w2];
    v += add;
    if (t < nb) bsum[t] = v - s;
}

__global__ __launch_bounds__(256) void k_scan_c(int* __restrict__ offs, const int* __restrict__ bsum,
                                                int* __restrict__ cursor, const int* __restrict__ deg,
                                                float* __restrict__ invd, int N){
    int i = blockIdx.x * 256 + threadIdx.x;
    if (i >= N) return;
    int v = offs[i] + bsum[i >> 10];
    offs[i] = v; cursor[i] = v;
    int d = deg[i];
    invd[i] = d > 0 ? 1.0f / (float)d : 0.0f;
}

__global__ __launch_bounds__(256) void k_scatter(const int* __restrict__ row, const int* __restrict__ col,
                                                 const void* __restrict__ ea, int* __restrict__ cursor,
                                                 int* __restrict__ colS, float* __restrict__ eaS,
                                                 const int* __restrict__ flag, int E){
    int e = blockIdx.x * 256 + threadIdx.x;
    if (e >= E) return;
    int bf = *flag;
    float av = bf ? b2f(((const u16*)ea)[e]) : ((const float*)ea)[e];
    int r = row[e];
    int pos = atomicAdd(&cursor[r], 1);
    colS[pos] = col[e];
    eaS[pos] = av;
}

// t_i[n] = invd[n] * sum_e relu(ea*w3_i + b3_i), i=0..2
__global__ __launch_bounds__(256) void k_tee(const int* __restrict__ offs, const int* __restrict__ deg,
                                             const float* __restrict__ invd, const float* __restrict__ eaS,
                                             const float* __restrict__ wc, float* __restrict__ t3, int N){
    int n = blockIdx.x * 256 + threadIdx.x;
    if (n >= N) return;
    float w0 = wc[OL3W + 0], w1 = wc[OL3W + 1], w2 = wc[OL3W + 2];
    float c0 = wc[OL3B + 0], c1 = wc[OL3B + 1], c2 = wc[OL3B + 2];
    int e = offs[n], ee = e + deg[n];
    float s0 = 0.f, s1 = 0.f, s2 = 0.f;
    for (; e < ee; ++e){
        float a = eaS[e];
        s0 += fmaxf(a * w0 + c0, 0.f);
        s1 += fmaxf(a * w1 + c1, 0.f);
        s2 += fmaxf(a * w2 + c2, 0.f);
    }
    float iv = invd[n];
    t3[n] = s0 * iv; t3[N + n] = s1 * iv; t3[2 * N + n] = s2 * iv;
}

// transpose canonical l1_w into n-major bf16 [3][128][128]; basev[i][h] = l0b+l1b+l2b
__global__ __launch_bounds__(128) void k_prepw(const float* __restrict__ wc,
                                               u16* __restrict__ w1t, float* __restrict__ basev){
    int i = blockIdx.x >> 7;
    int n = blockIdx.x & 127;
    int k = threadIdx.x;
    w1t[(i * 128 + n) * 128 + k] = f2b(wc[OL1W + (i * 128 + k) * 128 + n]);
    if (n == 0)
        basev[i * 128 + k] = wc[OL0B + i * 128 + k] + wc[OL1B + i * 128 + k] + wc[OL2B + i * 128 + k];
}

// hop 0: u = relu(x*w0 + t0*w2 + base) (u_agg == 0)
__global__ __launch_bounds__(256) void k_hop0(const float* __restrict__ xc, const float* __restrict__ t0,
                                              const float* __restrict__ l0wc, const float* __restrict__ l2wc,
                                              const float* __restrict__ basev, u32* __restrict__ uOut, int N){
    int idx = blockIdx.x * 256 + threadIdx.x;
    if (idx >= N * 64) return;
    int n = idx >> 6;
    int ch = (idx & 63) * 2;
    float xv = xc[n];
    float tv = t0[n];
    float v0 = fmaxf(xv * l0wc[ch]     + tv * l2wc[ch]     + basev[ch],     0.f);
    float v1 = fmaxf(xv * l0wc[ch + 1] + tv * l2wc[ch + 1] + basev[ch + 1], 0.f);
    uOut[idx] = (u32)f2b(v0) | ((u32)f2b(v1) << 16);
}

// fused per-hop: gather-mean -> LDS A-tile -> MFMA with W1^T -> +rank1 terms -> relu
__global__ __launch_bounds__(256) void k_hop(const u16* __restrict__ uPrev, u16* __restrict__ uNext,
    const int* __restrict__ colS, const float* __restrict__ eaS,
    const int* __restrict__ offs, const int* __restrict__ deg, const float* __restrict__ invd,
    const u16* __restrict__ w1t, const float* __restrict__ basev,
    const float* __restrict__ l0wc, const float* __restrict__ l2wc,
    const float* __restrict__ xc, const float* __restrict__ t_i, int N)
{
    __shared__ __align__(16) u16 A[64][136];
    __shared__ __align__(16) u16 W[128][136];
    int tid = threadIdx.x;
    int lane = tid & 63, wid = tid >> 6;
    int n0 = blockIdx.x * 64;

    #pragma unroll
    for (int it = 0; it < 8; ++it){
        int el = (it * 256 + tid) * 8;
        int n = el >> 7, k = el & 127;
        uint4 v = *(const uint4*)(w1t + el);
        *(uint4*)&W[n][k] = v;
    }

    int ch = lane * 2;
    for (int r = 0; r < 16; ++r){
        int n = n0 + wid * 16 + r;
        float a0 = 0.f, a1 = 0.f;
        if (n < N){
            int e = offs[n], ee = e + deg[n];
            for (; e < ee; ++e){
                int c = colS[e];
                float wgt = eaS[e];
                u32 pv = *(const u32*)(uPrev + (size_t)c * 128 + ch);
                a0 += wgt * b2f((u16)(pv & 0xffffu));
                a1 += wgt * b2f((u16)(pv >> 16));
            }
            float s = invd[n];
            a0 *= s; a1 *= s;
        }
        *(u32*)&A[wid * 16 + r][ch] = (u32)f2b(a0) | ((u32)f2b(a1) << 16);
    }
    __syncthreads();

    f32x4 acc[4][2];
    #pragma unroll
    for (int mt = 0; mt < 4; ++mt)
        #pragma unroll
        for (int nt = 0; nt < 2; ++nt) acc[mt][nt] = (f32x4){0.f, 0.f, 0.f, 0.f};
    int mrow = lane & 15, kq = lane >> 4;
    #pragma unroll
    for (int kk = 0; kk < 4; ++kk){
        int kb = kk * 32 + kq * 8;
        bf16x8 af[4], bf[2];
        #pragma unroll
        for (int mt = 0; mt < 4; ++mt) af[mt] = *(const bf16x8*)&A[mt * 16 + mrow][kb];
        #pragma unroll
        for (int nt = 0; nt < 2; ++nt) bf[nt] = *(const bf16x8*)&W[wid * 32 + nt * 16 + mrow][kb];
        #pragma unroll
        for (int mt = 0; mt < 4; ++mt)
            #pragma unroll
            for (int nt = 0; nt < 2; ++nt)
                acc[mt][nt] = __builtin_amdgcn_mfma_f32_16x16x32_bf16(af[mt], bf[nt], acc[mt][nt], 0, 0, 0);
    }

    float w0c[2], w2c[2], bc[2]; int colv[2];
    #pragma unroll
    for (int nt = 0; nt < 2; ++nt){
        int col = wid * 32 + nt * 16 + mrow;
        colv[nt] = col;
        w0c[nt] = l0wc[col]; w2c[nt] = l2wc[col]; bc[nt] = basev[col];
    }
    #pragma unroll
    for (int mt = 0; mt < 4; ++mt){
        #pragma unroll
        for (int rg = 0; rg < 4; ++rg){
            int n = n0 + mt * 16 + kq * 4 + rg;
            if (n < N){
                float xv = xc[n];
                float tv = t_i[n];
                #pragma unroll
                for (int nt = 0; nt < 2; ++nt){
                    float v = acc[mt][nt][rg] + xv * w0c[nt] + tv * w2c[nt] + bc[nt];
                    uNext[(size_t)n * 128 + colv[nt]] = f2b(fmaxf(v, 0.f));
                }
            }
        }
    }
}

// ---------------- readout ----------------

static __device__ __forceinline__ int lowbound(const int* b, int n, int g){
    int lo = 0, hi = n;
    while (lo < hi){ int m = (lo + hi) >> 1; if (b[m] < g) lo = m + 1; else hi = m; }
    return lo;
}

__global__ __launch_bounds__(128) void k_pool(const u16* __restrict__ u, const float* __restrict__ xc,
                                              const int* __restrict__ batch,
                                              float* __restrict__ S0, float* __restrict__ S1,
                                              int* __restrict__ cnt1, int N){
    int g = blockIdx.x >> 3, sl = blockIdx.x & 7;
    int t = threadIdx.x;
    int st = lowbound(batch, N, g), en = lowbound(batch, N, g + 1);
    int len = en - st;
    int chunk = (len + 7) >> 3;
    int ns = st + sl * chunk;
    int ne = min(ns + chunk, en);
    float s0 = 0.f, s1 = 0.f; int c1 = 0;
    for (int n = ns; n < ne; ++n){
        float xv = xc[n];
        float v = b2f(u[(size_t)n * 128 + t]);
        if (xv > 0.5f){ s1 += v; c1++; } else { s0 += v; }
    }
    atomicAdd(&S0[g * 128 + t], s0);
    atomicAdd(&S1[g * 128 + t], s1);
    if (t == 0) atomicAdd(&cnt1[g], c1);
}

__global__ __launch_bounds__(128) void k_poolfin(const float* __restrict__ S0, const float* __restrict__ S1,
                                                 const int* __restrict__ cnt1, const int* __restrict__ batch,
                                                 float* __restrict__ hc0, float* __restrict__ hc1, int N){
    int g = blockIdx.x, t = threadIdx.x;
    int st = lowbound(batch, N, g), en = lowbound(batch, N, g + 1);
    int c1 = cnt1[g], c0 = (en - st) - c1;
    hc0[g * 128 + t] = c0 > 0 ? S0[g * 128 + t] / (float)c0 : 0.f;
    hc1[g * 128 + t] = c1 > 0 ? S1[g * 128 + t] / (float)c1 : 0.f;
}

__global__ __launch_bounds__(256) void k_fold(const float* __restrict__ wc,
                                              float* __restrict__ spf, float* __restrict__ acf,
                                              float* __restrict__ biasv){
    int t = threadIdx.x;
    float s = 0.f;
    for (int o = 0; o < 128; ++o) s += wc[OACW + t * 128 + o] * wc[OLASTW + 128 + o];
    acf[t] = s;
    if (t < 128){
        float s2 = 0.f;
        for (int o = 0; o < 128; ++o) s2 += wc[OSPW + t * 128 + o] * wc[OLASTW + o];
        spf[t] = s2;
    }
    if (t == 0){
        float b = wc[OLASTB];
        for (int o = 0; o < 128; ++o)
            b += wc[OSPB + o] * wc[OLASTW + o] + wc[OACB + o] * wc[OLASTW + 128 + o];
        biasv[0] = b;
    }
}

__global__ __launch_bounds__(256) void k_graphvec(const float* __restrict__ wc,
                                                  const float* __restrict__ hc0, const float* __restrict__ hc1,
                                                  float* __restrict__ v0, float* __restrict__ v1){
    int g = blockIdx.x, j = threadIdx.x;
    float a0 = 0.f, a1 = 0.f;
    for (int o = 0; o < 128; ++o){
        float w = wc[OATTW + j * 128 + o];
        a0 += w * hc0[g * 128 + o];
        a1 += w * hc1[g * 128 + o];
    }
    v0[g * 256 + j] = a0; v1[g * 256 + j] = a1;
}

__global__ __launch_bounds__(64) void k_gscal(const float* __restrict__ v0, const float* __restrict__ v1,
                                              const float* __restrict__ hc0, const float* __restrict__ hc1,
                                              const float* __restrict__ wc, const float* __restrict__ spf,
                                              const float* __restrict__ acf, float* __restrict__ gsc){
    int g = blockIdx.x, l = threadIdx.x;
    float p[10];
    #pragma unroll
    for (int k = 0; k < 10; ++k) p[k] = 0.f;
    #pragma unroll
    for (int rep = 0; rep < 2; ++rep){
        int o = l + rep * 64;
        float h0 = hc0[g * 128 + o], h1 = hc1[g * 128 + o];
        float q0 = v0[g * 256 + 128 + o], q1 = v1[g * 256 + 128 + o];
        float ab = wc[OATTB + o];
        float sf = spf[o], af = acf[128 + o];
        p[0] += q0 * h0; p[1] += q0 * h1;
        p[2] += q1 * h0; p[3] += q1 * h1;
        p[4] += ab * h0; p[5] += ab * h1;
        p[6] += sf * h0; p[7] += sf * h1;
        p[8] += af * h0; p[9] += af * h1;
    }
    #pragma unroll
    for (int m = 1; m < 64; m <<= 1){
        #pragma unroll
        for (int k = 0; k < 10; ++k) p[k] += __shfl_xor(p[k], m);
    }
    if (l == 0){
        #pragma unroll
        for (int k = 0; k < 10; ++k) gsc[g * 10 + k] = p[k];
    }
}

__global__ __launch_bounds__(256) void k_final(const u16* __restrict__ u, const float* __restrict__ xc,
                                               const int* __restrict__ batch,
                                               const float* __restrict__ v0, const float* __restrict__ v1,
                                               const float* __restrict__ acf, const float* __restrict__ gsc,
                                               const float* __restrict__ biasv, const int* __restrict__ flag,
                                               void* __restrict__ out, int N){
    int bf = *flag;
    int wid = threadIdx.x >> 6, lane = threadIdx.x & 63;
    int n = blockIdx.x * 4 + wid;
    if (n >= N) return;
    int g = batch[n];
    int ch = lane * 2;
    u32 uv = *(const u32*)(u + (size_t)n * 128 + ch);
    float u0 = b2f((u16)(uv & 0xffffu)), u1 = b2f((u16)(uv >> 16));
    float2 a = *(const float2*)(v0 + g * 256 + ch);
    float2 b = *(const float2*)(v1 + g * 256 + ch);
    float2 c = *(const float2*)(acf + ch);
    float r0 = u0 * a.x + u1 * a.y;
    float r1 = u0 * b.x + u1 * b.y;
    float rA = u0 * c.x + u1 * c.y;
    #pragma unroll
    for (int m = 1; m < 64; m <<= 1){
        r0 += __shfl_xor(r0, m);
        r1 += __shfl_xor(r1, m);
        rA += __shfl_xor(rA, m);
    }
    if (lane == 0){
        const float* G = gsc + g * 10;
        bool xv = xc[n] > 0.5f;
        float z0 = r0 + (xv ? G[0] : G[1]) + G[4];
        float z1 = r1 + (xv ? G[2] : G[3]) + G[5];
        float mz = fmaxf(z0, z1);
        float e0 = expf(z0 - mz), e1 = expf(z1 - mz);
        float inv = 1.f / (e0 + e1);
        float q = (e0 * G[6] + e1 * G[7]) * inv + rA + (xv ? G[8] : G[9]) + biasv[0];
        if (bf) ((u16*)out)[n] = f2b(q);
        else    ((float*)out)[n] = q;
    }
}

// ---------------- host ----------------

extern "C" void kernel_launch(void* const* d_in, const int* in_sizes, int n_in,
                              void* d_out, int out_size, void* d_ws, size_t ws_size,
                              hipStream_t stream)
{
    const void* x    = d_in[0];
    const int* ei    = (const int*)d_in[1];
    const void* ea   = d_in[2];
    const int* batch = (const int*)d_in[3];
    // d_in[4] = num_graphs (B=64 fixed)
    Ptrs16 wp;
    for (int i = 0; i < 16; ++i) wp.p[i] = d_in[5 + i];

    int N = in_sizes[0];
    int E = in_sizes[2];
    const int* rowI = ei;
    const int* colI = ei + E;

    char* w = (char*)d_ws;
    size_t o = 0;
    auto alloc = [&](size_t b) -> char* {
        char* p = w + o; o = (o + b + 255) & ~(size_t)255; return p;
    };
    // small buffers first
    int*   flag   = (int*)alloc(4);
    int*   bsum   = (int*)alloc(256 * 4);
    float* basev  = (float*)alloc(3 * 128 * 4);
    float* spf    = (float*)alloc(128 * 4);
    float* acf    = (float*)alloc(256 * 4);
    float* biasv  = (float*)alloc(4);
    float* gsc    = (float*)alloc(64 * 10 * 4);
    float* S0     = (float*)alloc(64 * 128 * 4);
    float* S1     = (float*)alloc(64 * 128 * 4);
    int*   cnt1   = (int*)alloc(64 * 4);
    float* hc0    = (float*)alloc(64 * 128 * 4);
    float* hc1    = (float*)alloc(64 * 128 * 4);
    float* v0     = (float*)alloc(64 * 256 * 4);
    float* v1     = (float*)alloc(64 * 256 * 4);
    float* wc     = (float*)alloc((size_t)WTOT * 4);
    float* xc     = (float*)alloc((size_t)N * 4);
    int*   deg    = (int*)alloc((size_t)N * 4);
    int*   offs   = (int*)alloc((size_t)N * 4);
    int*   cursor = (int*)alloc((size_t)N * 4);
    float* invd   = (float*)alloc((size_t)N * 4);
    float* t3     = (float*)alloc((size_t)3 * N * 4);
    u16*   w1t    = (u16*)alloc((size_t)3 * 128 * 128 * 2);
    int*   colS   = (int*)alloc((size_t)E * 4);
    float* eaS    = (float*)alloc((size_t)E * 4);
    u16*   uA     = (u16*)alloc((size_t)N * 128 * 2);
    u16*   uB     = (u16*)alloc((size_t)N * 128 * 2);
    (void)ws_size; (void)n_in; (void)out_size;

    hipMemsetAsync(deg, 0, (size_t)N * 4, stream);
    hipMemsetAsync(S0, 0, 64 * 128 * 4, stream);
    hipMemsetAsync(S1, 0, 64 * 128 * 4, stream);
    hipMemsetAsync(cnt1, 0, 64 * 4, stream);

    int gE = (E + 255) / 256;
    int gN = (N + 255) / 256;
    int G1 = (N + 1023) / 1024;
    int nwords = (N / 2 < 512) ? (N / 2) : 512;

    k_detect<<<1, 512, 0, stream>>>((const u32*)x, flag, nwords);
    k_canon<<<(WTOT + N + 255) / 256, 256, 0, stream>>>(wp, x, wc, xc, flag, N);

    k_hist<<<gE, 256, 0, stream>>>(rowI, deg, E);
    k_scan_a<<<G1, 256, 0, stream>>>(deg, offs, bsum, N);
    k_scan_b<<<1, 256, 0, stream>>>(bsum, G1);
    k_scan_c<<<gN, 256, 0, stream>>>(offs, bsum, cursor, deg, invd, N);
    k_scatter<<<gE, 256, 0, stream>>>(rowI, colI, ea, cursor, colS, eaS, flag, E);
    k_tee<<<gN, 256, 0, stream>>>(offs, deg, invd, eaS, wc, t3, N);
    k_prepw<<<3 * 128, 128, 0, stream>>>(wc, w1t, basev);
    k_fold<<<1, 256, 0, stream>>>(wc, spf, acf, biasv);

    k_hop0<<<(N * 64 + 255) / 256, 256, 0, stream>>>(xc, t3, wc + OL0W, wc + OL2W, basev, (u32*)uA, N);

    int gHop = (N + 63) / 64;
    k_hop<<<gHop, 256, 0, stream>>>(uA, uB, colS, eaS, offs, deg, invd,
                                    w1t + 1 * 16384, basev + 128, wc + OL0W + 128, wc + OL2W + 128,
                                    xc, t3 + N, N);
    k_hop<<<gHop, 256, 0, stream>>>(uB, uA, colS, eaS, offs, deg, invd,
                                    w1t + 2 * 16384, basev + 256, wc + OL0W + 256, wc + OL2W + 256,
                                    xc, t3 + 2 * N, N);

    k_pool<<<64 * 8, 128, 0, stream>>>(uA, xc, batch, S0, S1, cnt1, N);
    k_poolfin<<<64, 128, 0, stream>>>(S0, S1, cnt1, batch, hc0, hc1, N);
    k_graphvec<<<64, 256, 0, stream>>>(wc, hc0, hc1, v0, v1);
    k_gscal<<<64, 64, 0, stream>>>(v0, v1, hc0, hc1, wc, spf, acf, gsc);
    k_final<<<(N + 3) / 4, 256, 0, stream>>>(uA, xc, batch, v0, v1, acf, gsc, biasv, flag, d_out, N);
}

// Round 3
// 501.276 us; speedup vs baseline: 1.6430x; 1.6430x over previous
//
#include <hip/hip_runtime.h>
#include <stdint.h>

typedef unsigned int  u32;
typedef unsigned short u16;

typedef short bf16x8 __attribute__((ext_vector_type(8)));
typedef float f32x4  __attribute__((ext_vector_type(4)));

static __device__ __forceinline__ float b2f(u16 h){
    union { u32 u; float f; } v; v.u = ((u32)h) << 16; return v.f;
}
static __device__ __forceinline__ float b2f_hi(u32 w){
    union { u32 u; float f; } v; v.u = w & 0xFFFF0000u; return v.f;
}
static __device__ __forceinline__ float b2f_lo(u32 w){
    union { u32 u; float f; } v; v.u = w << 16; return v.f;
}
static __device__ __forceinline__ u16 f2b(float f){
    union { float f; u32 u; } v; v.f = f;
    u32 r = v.u + 0x7FFFu + ((v.u >> 16) & 1u);
    return (u16)(r >> 16);
}

// canonical fp32 weight block offsets (floats)
#define OL0W 0
#define OL0B 384
#define OL1W 768
#define OL1B 49920
#define OL2W 50304
#define OL2B 50688
#define OL3W 51072
#define OL3B 51075
#define OATTW 51078
#define OATTB 83846
#define OSPW 83974
#define OSPB 100358
#define OACW 100486
#define OACB 133254
#define OLASTW 133382
#define OLASTB 133638
#define WTOT 133639

struct Ptrs16 { const void* p[16]; };

// wave-uniform dtype probe: x is exactly {0,1}; fp32 words have low16==0,
// bf16-pair words have low16==0x3F80 for ~half the words.
static __device__ __forceinline__ int detect_bf(const u32* __restrict__ xw){
    int lane = threadIdx.x & 63;
    int f = 0;
    #pragma unroll
    for (int i = 0; i < 8; ++i){
        u32 w = xw[lane * 8 + i];
        f |= ((w & 0xFFFFu) == 0x3F80u) ? 1 : 0;
    }
    return __ballot(f) != 0ull;
}

// canonicalize all weights + x to fp32; block 0 publishes flag
__global__ __launch_bounds__(256) void k_canon(Ptrs16 wp, const void* __restrict__ xin,
                                               float* __restrict__ wc, float* __restrict__ xc,
                                               int* __restrict__ flag, int N){
    int bf = detect_bf((const u32*)xin);
    int i = blockIdx.x * 256 + threadIdx.x;
    if (i == 0) *flag = bf;
    const int sz[16] = {384,384,49152,384,384,384,3,3,32768,128,16384,128,32768,128,256,1};
    if (i < WTOT){
        int seg = 0, off = i;
        while (off >= sz[seg]){ off -= sz[seg]; ++seg; }
        wc[i] = bf ? b2f(((const u16*)wp.p[seg])[off]) : ((const float*)wp.p[seg])[off];
    } else {
        int n = i - WTOT;
        if (n < N) xc[n] = bf ? b2f(((const u16*)xin)[n]) : ((const float*)xin)[n];
    }
}

// ---------------- counting sort of edges by row ----------------

__global__ __launch_bounds__(256) void k_hist(const int* __restrict__ row, int* __restrict__ deg, int E){
    int e = blockIdx.x * 256 + threadIdx.x;
    if (e < E) atomicAdd(&deg[row[e]], 1);
}

__global__ __launch_bounds__(256) void k_scan_a(const int* __restrict__ deg, int* __restrict__ offs,
                                                int* __restrict__ bsum, int N){
    int t = threadIdx.x, b = blockIdx.x;
    int i0 = b * 1024 + t * 4;
    int d0 = (i0 + 0 < N) ? deg[i0 + 0] : 0;
    int d1 = (i0 + 1 < N) ? deg[i0 + 1] : 0;
    int d2 = (i0 + 2 < N) ? deg[i0 + 2] : 0;
    int d3 = (i0 + 3 < N) ? deg[i0 + 3] : 0;
    int s = d0 + d1 + d2 + d3;
    int lane = t & 63, wid = t >> 6;
    int v = s;
    #pragma unroll
    for (int d = 1; d < 64; d <<= 1){ int o = __shfl_up(v, d); if (lane >= d) v += o; }
    __shared__ int wsum[4];
    if (lane == 63) wsum[wid] = v;
    __syncthreads();
    int add = 0;
    for (int w2 = 0; w2 < wid; ++w2) add += wsum[w2];
    v += add;
    int ex = v - s;
    if (i0 + 0 < N) offs[i0 + 0] = ex; ex += d0;
    if (i0 + 1 < N) offs[i0 + 1] = ex; ex += d1;
    if (i0 + 2 < N) offs[i0 + 2] = ex; ex += d2;
    if (i0 + 3 < N) offs[i0 + 3] = ex;
    if (t == 255) bsum[b] = v;
}

__global__ __launch_bounds__(256) void k_scan_b(int* __restrict__ bsum, int nb){
    int t = threadIdx.x;
    int s = (t < nb) ? bsum[t] : 0;
    int lane = t & 63, wid = t >> 6;
    int v = s;
    #pragma unroll
    for (int d = 1; d < 64; d <<= 1){ int o = __shfl_up(v, d); if (lane >= d) v += o; }
    __shared__ int wsum[4];
    if (lane == 63) wsum[wid] = v;
    __syncthreads();
    int add = 0;
    for (int w2 = 0; w2 < wid; ++w2) add += wsum[w2];
    v += add;
    if (t < nb) bsum[t] = v - s;
}

__global__ __launch_bounds__(256) void k_scan_c(int* __restrict__ offs, const int* __restrict__ bsum,
                                                int* __restrict__ cursor, const int* __restrict__ deg,
                                                float* __restrict__ invd, int N){
    int i = blockIdx.x * 256 + threadIdx.x;
    if (i >= N) return;
    int v = offs[i] + bsum[i >> 10];
    offs[i] = v; cursor[i] = v;
    int d = deg[i];
    invd[i] = d > 0 ? 1.0f / (float)d : 0.0f;
}

__global__ __launch_bounds__(256) void k_scatter(const int* __restrict__ row, const int* __restrict__ col,
                                                 const void* __restrict__ ea, int* __restrict__ cursor,
                                                 int* __restrict__ colS, float* __restrict__ eaS,
                                                 const int* __restrict__ flag, int E){
    int e = blockIdx.x * 256 + threadIdx.x;
    if (e >= E) return;
    int bf = *flag;
    float av = bf ? b2f(((const u16*)ea)[e]) : ((const float*)ea)[e];
    int r = row[e];
    int pos = atomicAdd(&cursor[r], 1);
    colS[pos] = col[e];
    eaS[pos] = av;
}

// t_i[n] = invd[n] * sum_e relu(ea*w3_i + b3_i), i=0..2
__global__ __launch_bounds__(256) void k_tee(const int* __restrict__ offs, const int* __restrict__ deg,
                                             const float* __restrict__ invd, const float* __restrict__ eaS,
                                             const float* __restrict__ wc, float* __restrict__ t3, int N){
    int n = blockIdx.x * 256 + threadIdx.x;
    if (n >= N) return;
    float w0 = wc[OL3W + 0], w1 = wc[OL3W + 1], w2 = wc[OL3W + 2];
    float c0 = wc[OL3B + 0], c1 = wc[OL3B + 1], c2 = wc[OL3B + 2];
    int e = offs[n], ee = e + deg[n];
    float s0 = 0.f, s1 = 0.f, s2 = 0.f;
    for (; e < ee; ++e){
        float a = eaS[e];
        s0 += fmaxf(a * w0 + c0, 0.f);
        s1 += fmaxf(a * w1 + c1, 0.f);
        s2 += fmaxf(a * w2 + c2, 0.f);
    }
    float iv = invd[n];
    t3[n] = s0 * iv; t3[N + n] = s1 * iv; t3[2 * N + n] = s2 * iv;
}

// transpose canonical l1_w into n-major bf16 [3][128][128]; basev[i][h] = l0b+l1b+l2b
__global__ __launch_bounds__(128) void k_prepw(const float* __restrict__ wc,
                                               u16* __restrict__ w1t, float* __restrict__ basev){
    int i = blockIdx.x >> 7;
    int n = blockIdx.x & 127;
    int k = threadIdx.x;
    w1t[(i * 128 + n) * 128 + k] = f2b(wc[OL1W + (i * 128 + k) * 128 + n]);
    if (n == 0)
        basev[i * 128 + k] = wc[OL0B + i * 128 + k] + wc[OL1B + i * 128 + k] + wc[OL2B + i * 128 + k];
}

// hop 0: u = relu(x*w0 + t0*w2 + base) (u_agg == 0)
__global__ __launch_bounds__(256) void k_hop0(const float* __restrict__ xc, const float* __restrict__ t0,
                                              const float* __restrict__ l0wc, const float* __restrict__ l2wc,
                                              const float* __restrict__ basev, u32* __restrict__ uOut, int N){
    int idx = blockIdx.x * 256 + threadIdx.x;
    if (idx >= N * 64) return;
    int n = idx >> 6;
    int ch = (idx & 63) * 2;
    float xv = xc[n];
    float tv = t0[n];
    float v0 = fmaxf(xv * l0wc[ch]     + tv * l2wc[ch]     + basev[ch],     0.f);
    float v1 = fmaxf(xv * l0wc[ch + 1] + tv * l2wc[ch + 1] + basev[ch + 1], 0.f);
    uOut[idx] = (u32)f2b(v0) | ((u32)f2b(v1) << 16);
}

// fused per-hop: edge-parallel gather-mean -> LDS A-tile -> MFMA (B frags in regs) -> rank1 -> relu
// 256 threads = 4 waves, 32-node tile. Wave = 16 channel-groups x 4 edge-groups.
__global__ __launch_bounds__(256) void k_hop(const u16* __restrict__ uPrev, u16* __restrict__ uNext,
    const int* __restrict__ colS, const float* __restrict__ eaS,
    const int* __restrict__ offs, const int* __restrict__ deg, const float* __restrict__ invd,
    const u16* __restrict__ w1t, const float* __restrict__ basev,
    const float* __restrict__ l0wc, const float* __restrict__ l2wc,
    const float* __restrict__ xc, const float* __restrict__ t_i, int N)
{
    __shared__ __align__(16) u16 A[32][136];
    int tid = threadIdx.x;
    int lane = tid & 63, wid = tid >> 6;      // wid 0..3
    int n0 = blockIdx.x * 32;
    int cid = lane & 15, grp = lane >> 4;     // also mrow / kq for MFMA

    // preload B fragments: wave wid covers output cols [wid*32, wid*32+32)
    bf16x8 bfr[4][2];
    #pragma unroll
    for (int kk = 0; kk < 4; ++kk)
        #pragma unroll
        for (int nt = 0; nt < 2; ++nt)
            bfr[kk][nt] = *(const bf16x8*)(w1t + (size_t)(wid * 32 + nt * 16 + cid) * 128 + kk * 32 + grp * 8);

    // gather: wave wid handles nodes [n0+8*wid, +8); 4 edges in flight, 16B/lane
    for (int r = 0; r < 8; ++r){
        int n = n0 + wid * 8 + r;
        float acc[8];
        #pragma unroll
        for (int j = 0; j < 8; ++j) acc[j] = 0.f;
        if (n < N){
            int e0 = offs[n], e1 = e0 + deg[n];
            for (int e = e0 + grp; e < e1; e += 4){
                int c = colS[e];
                float wgt = eaS[e];
                uint4 pv = *(const uint4*)(uPrev + (size_t)c * 128 + cid * 8);
                acc[0] += wgt * b2f_lo(pv.x); acc[1] += wgt * b2f_hi(pv.x);
                acc[2] += wgt * b2f_lo(pv.y); acc[3] += wgt * b2f_hi(pv.y);
                acc[4] += wgt * b2f_lo(pv.z); acc[5] += wgt * b2f_hi(pv.z);
                acc[6] += wgt * b2f_lo(pv.w); acc[7] += wgt * b2f_hi(pv.w);
            }
        }
        // combine the 4 edge-groups
        #pragma unroll
        for (int j = 0; j < 8; ++j){
            acc[j] += __shfl_xor(acc[j], 16);
            acc[j] += __shfl_xor(acc[j], 32);
        }
        if (grp == 0){
            float s = (n < N) ? invd[n] : 0.f;
            uint4 o;
            o.x = (u32)f2b(acc[0] * s) | ((u32)f2b(acc[1] * s) << 16);
            o.y = (u32)f2b(acc[2] * s) | ((u32)f2b(acc[3] * s) << 16);
            o.z = (u32)f2b(acc[4] * s) | ((u32)f2b(acc[5] * s) << 16);
            o.w = (u32)f2b(acc[6] * s) | ((u32)f2b(acc[7] * s) << 16);
            *(uint4*)&A[wid * 8 + r][cid * 8] = o;
        }
    }
    __syncthreads();

    // MFMA: wave wid computes cols [wid*32,+32) for rows 0..31
    f32x4 acc4[2][2];
    #pragma unroll
    for (int mt = 0; mt < 2; ++mt)
        #pragma unroll
        for (int nt = 0; nt < 2; ++nt) acc4[mt][nt] = (f32x4){0.f, 0.f, 0.f, 0.f};
    #pragma unroll
    for (int kk = 0; kk < 4; ++kk){
        int kb = kk * 32 + grp * 8;
        bf16x8 af[2];
        #pragma unroll
        for (int mt = 0; mt < 2; ++mt) af[mt] = *(const bf16x8*)&A[mt * 16 + cid][kb];
        #pragma unroll
        for (int mt = 0; mt < 2; ++mt)
            #pragma unroll
            for (int nt = 0; nt < 2; ++nt)
                acc4[mt][nt] = __builtin_amdgcn_mfma_f32_16x16x32_bf16(af[mt], bfr[kk][nt], acc4[mt][nt], 0, 0, 0);
    }

    // epilogue: D layout col=lane&15(+base), row=(lane>>4)*4+reg
    float w0c[2], w2c[2], bc[2]; int colv[2];
    #pragma unroll
    for (int nt = 0; nt < 2; ++nt){
        int col = wid * 32 + nt * 16 + cid;
        colv[nt] = col;
        w0c[nt] = l0wc[col]; w2c[nt] = l2wc[col]; bc[nt] = basev[col];
    }
    #pragma unroll
    for (int mt = 0; mt < 2; ++mt){
        #pragma unroll
        for (int rg = 0; rg < 4; ++rg){
            int n = n0 + mt * 16 + grp * 4 + rg;
            if (n < N){
                float xv = xc[n];
                float tv = t_i[n];
                #pragma unroll
                for (int nt = 0; nt < 2; ++nt){
                    float v = acc4[mt][nt][rg] + xv * w0c[nt] + tv * w2c[nt] + bc[nt];
                    uNext[(size_t)n * 128 + colv[nt]] = f2b(fmaxf(v, 0.f));
                }
            }
        }
    }
}

// ---------------- readout ----------------

static __device__ __forceinline__ int lowbound(const int* b, int n, int g){
    int lo = 0, hi = n;
    while (lo < hi){ int m = (lo + hi) >> 1; if (b[m] < g) lo = m + 1; else hi = m; }
    return lo;
}

__global__ __launch_bounds__(128) void k_pool(const u16* __restrict__ u, const float* __restrict__ xc,
                                              const int* __restrict__ batch,
                                              float* __restrict__ S0, float* __restrict__ S1,
                                              int* __restrict__ cnt1, int N){
    int g = blockIdx.x >> 3, sl = blockIdx.x & 7;
    int t = threadIdx.x;
    int st = lowbound(batch, N, g), en = lowbound(batch, N, g + 1);
    int len = en - st;
    int chunk = (len + 7) >> 3;
    int ns = st + sl * chunk;
    int ne = min(ns + chunk, en);
    float s0 = 0.f, s1 = 0.f; int c1 = 0;
    for (int n = ns; n < ne; ++n){
        float xv = xc[n];
        float v = b2f(u[(size_t)n * 128 + t]);
        if (xv > 0.5f){ s1 += v; c1++; } else { s0 += v; }
    }
    atomicAdd(&S0[g * 128 + t], s0);
    atomicAdd(&S1[g * 128 + t], s1);
    if (t == 0) atomicAdd(&cnt1[g], c1);
}

__global__ __launch_bounds__(256) void k_fold(const float* __restrict__ wc,
                                              float* __restrict__ spf, float* __restrict__ acf,
                                              float* __restrict__ biasv){
    int t = threadIdx.x;
    float s = 0.f;
    for (int o = 0; o < 128; ++o) s += wc[OACW + t * 128 + o] * wc[OLASTW + 128 + o];
    acf[t] = s;
    if (t < 128){
        float s2 = 0.f;
        for (int o = 0; o < 128; ++o) s2 += wc[OSPW + t * 128 + o] * wc[OLASTW + o];
        spf[t] = s2;
    }
    if (t == 0){
        float b = wc[OLASTB];
        for (int o = 0; o < 128; ++o)
            b += wc[OSPB + o] * wc[OLASTW + o] + wc[OACB + o] * wc[OLASTW + 128 + o];
        biasv[0] = b;
    }
}

// fused per-graph: hc0/hc1 -> v0/v1 -> 10 scalar folds. One block per graph.
__global__ __launch_bounds__(256) void k_graph(const float* __restrict__ S0, const float* __restrict__ S1,
                                               const int* __restrict__ cnt1, const int* __restrict__ batch,
                                               const float* __restrict__ wc, const float* __restrict__ spf,
                                               const float* __restrict__ acf,
                                               float* __restrict__ v0, float* __restrict__ v1,
                                               float* __restrict__ gsc, int N){
    __shared__ float h0[128], h1[128], sv0[128], sv1[128];
    int g = blockIdx.x, t = threadIdx.x;
    int st = lowbound(batch, N, g), en = lowbound(batch, N, g + 1);
    int c1 = cnt1[g], c0 = (en - st) - c1;
    if (t < 128){
        h0[t] = c0 > 0 ? S0[g * 128 + t] / (float)c0 : 0.f;
        h1[t] = c1 > 0 ? S1[g * 128 + t] / (float)c1 : 0.f;
    }
    __syncthreads();
    float a0 = 0.f, a1 = 0.f;
    for (int o = 0; o < 128; ++o){
        float w = wc[OATTW + t * 128 + o];
        a0 += w * h0[o];
        a1 += w * h1[o];
    }
    v0[g * 256 + t] = a0; v1[g * 256 + t] = a1;
    if (t >= 128){ sv0[t - 128] = a0; sv1[t - 128] = a1; }
    __syncthreads();
    if (t < 64){
        int l = t;
        float p[10];
        #pragma unroll
        for (int k = 0; k < 10; ++k) p[k] = 0.f;
        #pragma unroll
        for (int rep = 0; rep < 2; ++rep){
            int o = l + rep * 64;
            float hh0 = h0[o], hh1 = h1[o];
            float q0 = sv0[o], q1 = sv1[o];
            float ab = wc[OATTB + o];
            float sf = spf[o], af = acf[128 + o];
            p[0] += q0 * hh0; p[1] += q0 * hh1;
            p[2] += q1 * hh0; p[3] += q1 * hh1;
            p[4] += ab * hh0; p[5] += ab * hh1;
            p[6] += sf * hh0; p[7] += sf * hh1;
            p[8] += af * hh0; p[9] += af * hh1;
        }
        #pragma unroll
        for (int m = 1; m < 64; m <<= 1){
            #pragma unroll
            for (int k = 0; k < 10; ++k) p[k] += __shfl_xor(p[k], m);
        }
        if (l == 0){
            #pragma unroll
            for (int k = 0; k < 10; ++k) gsc[g * 10 + k] = p[k];
        }
    }
}

__global__ __launch_bounds__(256) void k_final(const u16* __restrict__ u, const float* __restrict__ xc,
                                               const int* __restrict__ batch,
                                               const float* __restrict__ v0, const float* __restrict__ v1,
                                               const float* __restrict__ acf, const float* __restrict__ gsc,
                                               const float* __restrict__ biasv, const int* __restrict__ flag,
                                               void* __restrict__ out, int N){
    int bf = *flag;
    int wid = threadIdx.x >> 6, lane = threadIdx.x & 63;
    int n = blockIdx.x * 4 + wid;
    if (n >= N) return;
    int g = batch[n];
    int ch = lane * 2;
    u32 uv = *(const u32*)(u + (size_t)n * 128 + ch);
    float u0 = b2f_lo(uv), u1 = b2f_hi(uv);
    float2 a = *(const float2*)(v0 + g * 256 + ch);
    float2 b = *(const float2*)(v1 + g * 256 + ch);
    float2 c = *(const float2*)(acf + ch);
    float r0 = u0 * a.x + u1 * a.y;
    float r1 = u0 * b.x + u1 * b.y;
    float rA = u0 * c.x + u1 * c.y;
    #pragma unroll
    for (int m = 1; m < 64; m <<= 1){
        r0 += __shfl_xor(r0, m);
        r1 += __shfl_xor(r1, m);
        rA += __shfl_xor(rA, m);
    }
    if (lane == 0){
        const float* G = gsc + g * 10;
        bool xv = xc[n] > 0.5f;
        float z0 = r0 + (xv ? G[0] : G[1]) + G[4];
        float z1 = r1 + (xv ? G[2] : G[3]) + G[5];
        float mz = fmaxf(z0, z1);
        float e0 = expf(z0 - mz), e1 = expf(z1 - mz);
        float inv = 1.f / (e0 + e1);
        float q = (e0 * G[6] + e1 * G[7]) * inv + rA + (xv ? G[8] : G[9]) + biasv[0];
        if (bf) ((u16*)out)[n] = f2b(q);
        else    ((float*)out)[n] = q;
    }
}

// ---------------- host ----------------

extern "C" void kernel_launch(void* const* d_in, const int* in_sizes, int n_in,
                              void* d_out, int out_size, void* d_ws, size_t ws_size,
                              hipStream_t stream)
{
    const void* x    = d_in[0];
    const int* ei    = (const int*)d_in[1];
    const void* ea   = d_in[2];
    const int* batch = (const int*)d_in[3];
    // d_in[4] = num_graphs (B=64 fixed)
    Ptrs16 wp;
    for (int i = 0; i < 16; ++i) wp.p[i] = d_in[5 + i];

    int N = in_sizes[0];
    int E = in_sizes[2];
    const int* rowI = ei;
    const int* colI = ei + E;

    char* w = (char*)d_ws;
    size_t o = 0;
    auto alloc = [&](size_t b) -> char* {
        char* p = w + o; o = (o + b + 255) & ~(size_t)255; return p;
    };
    int*   flag   = (int*)alloc(4);
    int*   bsum   = (int*)alloc(256 * 4);
    float* basev  = (float*)alloc(3 * 128 * 4);
    float* spf    = (float*)alloc(128 * 4);
    float* acf    = (float*)alloc(256 * 4);
    float* biasv  = (float*)alloc(4);
    float* gsc    = (float*)alloc(64 * 10 * 4);
    float* S0     = (float*)alloc(64 * 128 * 4);
    float* S1     = (float*)alloc(64 * 128 * 4);
    int*   cnt1   = (int*)alloc(64 * 4);
    float* v0     = (float*)alloc(64 * 256 * 4);
    float* v1     = (float*)alloc(64 * 256 * 4);
    float* wc     = (float*)alloc((size_t)WTOT * 4);
    float* xc     = (float*)alloc((size_t)N * 4);
    int*   deg    = (int*)alloc((size_t)N * 4);
    int*   offs   = (int*)alloc((size_t)N * 4);
    int*   cursor = (int*)alloc((size_t)N * 4);
    float* invd   = (float*)alloc((size_t)N * 4);
    float* t3     = (float*)alloc((size_t)3 * N * 4);
    u16*   w1t    = (u16*)alloc((size_t)3 * 128 * 128 * 2);
    int*   colS   = (int*)alloc((size_t)E * 4);
    float* eaS    = (float*)alloc((size_t)E * 4);
    u16*   uA     = (u16*)alloc((size_t)N * 128 * 2);
    u16*   uB     = (u16*)alloc((size_t)N * 128 * 2);
    (void)ws_size; (void)n_in; (void)out_size;

    hipMemsetAsync(deg, 0, (size_t)N * 4, stream);
    hipMemsetAsync(S0, 0, 64 * 128 * 4, stream);
    hipMemsetAsync(S1, 0, 64 * 128 * 4, stream);
    hipMemsetAsync(cnt1, 0, 64 * 4, stream);

    int gE = (E + 255) / 256;
    int gN = (N + 255) / 256;
    int G1 = (N + 1023) / 1024;

    k_canon<<<(WTOT + N + 255) / 256, 256, 0, stream>>>(wp, x, wc, xc, flag, N);

    k_hist<<<gE, 256, 0, stream>>>(rowI, deg, E);
    k_scan_a<<<G1, 256, 0, stream>>>(deg, offs, bsum, N);
    k_scan_b<<<1, 256, 0, stream>>>(bsum, G1);
    k_scan_c<<<gN, 256, 0, stream>>>(offs, bsum, cursor, deg, invd, N);
    k_scatter<<<gE, 256, 0, stream>>>(rowI, colI, ea, cursor, colS, eaS, flag, E);
    k_tee<<<gN, 256, 0, stream>>>(offs, deg, invd, eaS, wc, t3, N);
    k_prepw<<<3 * 128, 128, 0, stream>>>(wc, w1t, basev);
    k_fold<<<1, 256, 0, stream>>>(wc, spf, acf, biasv);

    k_hop0<<<(N * 64 + 255) / 256, 256, 0, stream>>>(xc, t3, wc + OL0W, wc + OL2W, basev, (u32*)uA, N);

    int gHop = (N + 31) / 32;
    k_hop<<<gHop, 256, 0, stream>>>(uA, uB, colS, eaS, offs, deg, invd,
                                    w1t + 1 * 16384, basev + 128, wc + OL0W + 128, wc + OL2W + 128,
                                    xc, t3 + N, N);
    k_hop<<<gHop, 256, 0, stream>>>(uB, uA, colS, eaS, offs, deg, invd,
                                    w1t + 2 * 16384, basev + 256, wc + OL0W + 256, wc + OL2W + 256,
                                    xc, t3 + 2 * N, N);

    k_pool<<<64 * 8, 128, 0, stream>>>(uA, xc, batch, S0, S1, cnt1, N);
    k_graph<<<64, 256, 0, stream>>>(S0, S1, cnt1, batch, wc, spf, acf, v0, v1, gsc, N);
    k_final<<<(N + 3) / 4, 256, 0, stream>>>(uA, xc, batch, v0, v1, acf, gsc, biasv, flag, d_out, N);
}